// Round 3
// baseline (240.694 us; speedup 1.0000x reference)
//
#include <hip/hip_runtime.h>
#include <stdint.h>

// Problem constants (fixed by setup_inputs)
#define BATCH 64
#define NPTS  131072
#define MPTS  2048
#define WORDS_PB (NPTS / 64)       // 2048 mask words per batch
#define P1_BLOCKS 2048             // 32 blocks per batch
#define SPAN  4096                 // contiguous points per block (4096*32 = NPTS)
#define STAGE 1024                 // points per LDS stage
#define NSTAGES (SPAN / STAGE)     // 4

#define GLOBAL_AS __attribute__((address_space(1)))
#define LDS_AS    __attribute__((address_space(3)))

// ---------------- Threefry-2x32-20, exactly as jax/_src/prng.py ----------------
struct U2 { uint32_t a, b; };

__host__ __device__ constexpr U2 tf2x32(uint32_t k0, uint32_t k1, uint32_t x0, uint32_t x1) {
  uint32_t ks0 = k0, ks1 = k1, ks2 = k0 ^ k1 ^ 0x1BD11BDAu;
  x0 += ks0; x1 += ks1;
  const int rotA[4] = {13, 15, 26, 6};
  const int rotB[4] = {17, 29, 16, 24};
  for (int r = 0; r < 4; ++r) { x0 += x1; x1 = (x1 << rotA[r]) | (x1 >> (32 - rotA[r])); x1 ^= x0; }
  x0 += ks1; x1 += ks2 + 1u;
  for (int r = 0; r < 4; ++r) { x0 += x1; x1 = (x1 << rotB[r]) | (x1 >> (32 - rotB[r])); x1 ^= x0; }
  x0 += ks2; x1 += ks0 + 2u;
  for (int r = 0; r < 4; ++r) { x0 += x1; x1 = (x1 << rotA[r]) | (x1 >> (32 - rotA[r])); x1 ^= x0; }
  x0 += ks0; x1 += ks1 + 3u;
  for (int r = 0; r < 4; ++r) { x0 += x1; x1 = (x1 << rotB[r]) | (x1 >> (32 - rotB[r])); x1 ^= x0; }
  x0 += ks1; x1 += ks2 + 4u;
  for (int r = 0; r < 4; ++r) { x0 += x1; x1 = (x1 << rotA[r]) | (x1 >> (32 - rotA[r])); x1 ^= x0; }
  x0 += ks2; x1 += ks0 + 5u;
  return U2{x0, x1};
}

// ---------------- Pass 1: async-DMA staged mask + per-block partial xyz sums ----------------
// Round-2 post-mortem: plain loads plateau at ~2.5 TB/s because the compiler
// serializes them (VGPR_Count=24 => <=3 loads in flight/wave => ~4 KB/CU
// outstanding vs the ~9.2 KB needed for 6.3 TB/s). Fix: stage each 1024-point
// chunk (16 KB pc + 8 KB logits) into LDS with __builtin_amdgcn_global_load_lds
// width=16 — payload bypasses VGPRs, 24 fire-and-forget DMA instrs per block
// stage, so outstanding bytes are set by LDS capacity (6 blocks/CU x 24 KB),
// not by the register allocator.
__global__ __launch_bounds__(256) void pass1_kernel(
    const float4* __restrict__ pc, const float* __restrict__ lg,
    float* __restrict__ sumsPartial, unsigned long long* __restrict__ maskWords) {
  __shared__ float4 sPC[STAGE];            // 16 KiB
  __shared__ float  sL0[STAGE];            // 4 KiB
  __shared__ float  sL1[STAGE];            // 4 KiB

  const int g = blockIdx.x;
  const int t = threadIdx.x;
  const int lane = t & 63, wv = t >> 6;
  const int b = g >> 5;                    // 32 blocks per batch
  const size_t base = (size_t)g * SPAN;    // global point index base
  const size_t inb  = base & (NPTS - 1);   // in-batch offset
  const float*  l0g = lg + (size_t)b * (2 * NPTS) + inb;
  const float*  l1g = l0g + NPTS;
  const float4* pcg = pc + base;

  float sx = 0.f, sy = 0.f, sz = 0.f;
  for (int s = 0; s < NSTAGES; ++s) {
    const int p0 = s * STAGE;
    // ---- issue stage DMA (async; no VGPR payload) ----
    // pc: wave wv, instr q covers points p0 + wv*256 + q*64 + lane (lane stride 16 B)
#pragma unroll
    for (int q = 0; q < 4; ++q) {
      const int pt = wv * 256 + q * 64;    // in-stage, lane added by HW on LDS side
      __builtin_amdgcn_global_load_lds(
          (const GLOBAL_AS void*)(pcg + (p0 + pt + lane)),
          (LDS_AS void*)((char*)sPC + (size_t)pt * 16), 16, 0, 0);
    }
    // logits: one 1 KiB instr per wave per row (lane loads 4 consecutive floats)
    __builtin_amdgcn_global_load_lds(
        (const GLOBAL_AS void*)(l0g + p0 + wv * 256 + lane * 4),
        (LDS_AS void*)((char*)sL0 + (size_t)(wv * 256) * 4), 16, 0, 0);
    __builtin_amdgcn_global_load_lds(
        (const GLOBAL_AS void*)(l1g + p0 + wv * 256 + lane * 4),
        (LDS_AS void*)((char*)sL1 + (size_t)(wv * 256) * 4), 16, 0, 0);

    __syncthreads();                       // compiler emits vmcnt(0) drain: DMA landed

    // ---- compute from LDS: thread t handles stage points {t, 256+t, 512+t, 768+t} ----
#pragma unroll
    for (int q = 0; q < 4; ++q) {
      const int ip = q * 256 + t;
      const float a0 = sL0[ip];
      const float a1 = sL1[ip];
      const float4 p = sPC[ip];
      const bool m = a0 < a1;
      const unsigned long long bal = __ballot(m);
      if (lane == 0)
        maskWords[(base + (size_t)(p0 + q * 256 + wv * 64)) >> 6] = bal;
      if (m) { sx += p.x; sy += p.y; sz += p.z; }
    }
    __syncthreads();                       // all LDS reads done before next stage overwrites
  }

  // wave (64-lane) reduce, then cross-wave via LDS
  for (int o = 32; o; o >>= 1) {
    sx += __shfl_down(sx, o, 64);
    sy += __shfl_down(sy, o, 64);
    sz += __shfl_down(sz, o, 64);
  }
  __shared__ float ssx[4], ssy[4], ssz[4];
  if (lane == 0) { ssx[wv] = sx; ssy[wv] = sy; ssz[wv] = sz; }
  __syncthreads();
  if (t == 0) {
    sumsPartial[g * 3 + 0] = ssx[0] + ssx[1] + ssx[2] + ssx[3];
    sumsPartial[g * 3 + 1] = ssy[0] + ssy[1] + ssy[2] + ssy[3];
    sumsPartial[g * 3 + 2] = ssz[0] + ssz[1] + ssz[2] + ssz[3];
  }
}

// ---------------- Pass 2 (fused scan + select + gather), unchanged from round 2 ----------------
__global__ __launch_bounds__(256) void pass3_kernel(
    const float4* __restrict__ pc, const float* __restrict__ sumsPartial,
    const unsigned long long* __restrict__ maskWords,
    float* __restrict__ out) {
  const int blk = blockIdx.x;
  const int b = blk >> 3;                  // 8 blocks per batch
  const int t = threadIdx.x;
  const int lane = t & 63, wv = t >> 6;
  const int j = (blk & 7) * 256 + t;
  const int gid = b * MPTS + j;

  __shared__ unsigned long long sW[WORDS_PB];   // 16 KiB
  __shared__ uint32_t sOff[WORDS_PB];           // 8 KiB
  __shared__ int wsum[4];
  __shared__ float sMean[3];
  __shared__ int sCnt;

  const unsigned long long* mw = maskWords + (size_t)b * WORDS_PB;
#pragma unroll
  for (int k = 0; k < 8; ++k) sW[t + k * 256] = mw[t + k * 256];
  __syncthreads();

  const int basew = t * 8;
  int p[8];
  int local = 0;
#pragma unroll
  for (int k = 0; k < 8; ++k) { p[k] = __popcll(sW[basew + k]); local += p[k]; }

  int x = local;
#pragma unroll
  for (int o = 1; o < 64; o <<= 1) {
    const int y = __shfl_up(x, o, 64);
    if (lane >= o) x += y;
  }
  if (lane == 63) wsum[wv] = x;
  __syncthreads();
  int add = 0;
#pragma unroll
  for (int u = 0; u < 4; ++u) add += (u < wv) ? wsum[u] : 0;
  int run = add + x - local;
#pragma unroll
  for (int k = 0; k < 8; ++k) { sOff[basew + k] = (uint32_t)run; run += p[k]; }

  if (t < 64) {
    float px = 0.f, py = 0.f, pz = 0.f;
    if (t < 32) {
      const float* sp = sumsPartial + ((size_t)b * 32 + t) * 3;
      px = sp[0]; py = sp[1]; pz = sp[2];
    }
    for (int o = 32; o; o >>= 1) {
      px += __shfl_down(px, o, 64);
      py += __shfl_down(py, o, 64);
      pz += __shfl_down(pz, o, 64);
    }
    if (t == 0) {
      const int ct = wsum[0] + wsum[1] + wsum[2] + wsum[3];
      sCnt = ct;
      const float d = fmaxf((float)ct, 1.0f);
      sMean[0] = px / d; sMean[1] = py / d; sMean[2] = pz / d;
      if ((blk & 7) == 0) {
        float* om = out + (size_t)BATCH * MPTS * 3 + (size_t)b * 3;
        om[0] = sMean[0]; om[1] = sMean[1]; om[2] = sMean[2];
      }
    }
  }
  __syncthreads();

  const int cb = sCnt;
  float ox, oy, oz;
  if (cb == 0) {
    ox = oy = oz = (float)b;
  } else {
    constexpr U2 K1 = tf2x32(0u, 42u, 0u, 0u);  // split(key)[0]
    constexpr U2 K2 = tf2x32(0u, 42u, 0u, 1u);  // split(key)[1]
    const uint32_t span = (uint32_t)cb;
    U2 h = tf2x32(K1.a, K1.b, 0u, (uint32_t)gid);
    U2 l = tf2x32(K2.a, K2.b, 0u, (uint32_t)gid);
    uint32_t hb = h.a ^ h.b;
    uint32_t lb = l.a ^ l.b;
    uint32_t mul = 65536u % span;
    mul = (mul * mul) % span;                   // uint32 wrap, exactly as lax
    uint32_t off = ((hb % span) * mul + (lb % span)) % span;
    int r = (j < cb && cb <= MPTS) ? j : (int)off;

    int lo = 0;
#pragma unroll
    for (int step = 1024; step; step >>= 1) {
      const int nxt = lo + step;
      if (nxt < WORDS_PB && sOff[nxt] <= (uint32_t)r) lo = nxt;
    }
    int rem = r - (int)sOff[lo];
    const unsigned long long w = sW[lo];

    uint32_t cur = (uint32_t)w;
    int bitbase = 0;
    int c = __popc(cur);
    if (rem >= c) { rem -= c; cur = (uint32_t)(w >> 32); bitbase = 32; }
    c = __popc(cur & 0xFFFFu); if (rem >= c) { rem -= c; cur >>= 16; bitbase += 16; }
    c = __popc(cur & 0xFFu);   if (rem >= c) { rem -= c; cur >>= 8;  bitbase += 8;  }
    c = __popc(cur & 0xFu);    if (rem >= c) { rem -= c; cur >>= 4;  bitbase += 4;  }
    c = __popc(cur & 0x3u);    if (rem >= c) { rem -= c; cur >>= 2;  bitbase += 2;  }
    c = (int)(cur & 1u);       if (rem >= c) {           cur >>= 1;  bitbase += 1;  }
    const int idx = lo * 64 + bitbase;

    const float4 pnt = pc[(size_t)b * NPTS + idx];
    ox = pnt.x - sMean[0]; oy = pnt.y - sMean[1]; oz = pnt.z - sMean[2];
  }
  float* o = out + (size_t)gid * 3;
  o[0] = ox; o[1] = oy; o[2] = oz;
}

// ---------------- launch ----------------
extern "C" void kernel_launch(void* const* d_in, const int* in_sizes, int n_in,
                              void* d_out, int out_size, void* d_ws, size_t ws_size,
                              hipStream_t stream) {
  const float4* pc = (const float4*)d_in[0];   // (B, N, 4) float32
  const float*  lg = (const float*)d_in[1];    // (B, 2, N) float32
  float* out = (float*)d_out;                  // obj (B,M,3) then mean (B,3)

  char* w = (char*)d_ws;
  float* sumsPartial = (float*)(w + 0);                    // 2048*3 floats = 24576 B
  unsigned long long* maskWords =
      (unsigned long long*)(w + 24576);                    // 64*2048 u64 = 1 MiB

  pass1_kernel<<<P1_BLOCKS, 256, 0, stream>>>(pc, lg, sumsPartial, maskWords);
  pass3_kernel<<<(BATCH * MPTS) / 256, 256, 0, stream>>>(pc, sumsPartial, maskWords, out);
}

// Round 5
// 237.875 us; speedup vs baseline: 1.0118x; 1.0118x over previous
//
#include <hip/hip_runtime.h>
#include <stdint.h>

// Problem constants (fixed by setup_inputs)
#define BATCH 64
#define NPTS  131072
#define MPTS  2048
#define WORDS_PB (NPTS / 64)       // 2048 mask words per batch
#define STAGE 1024                 // points per chunk / LDS stage
#define NCHUNKS ((BATCH * NPTS) / STAGE)   // 8192
#define CHUNKS_PB (NPTS / STAGE)   // 128 chunks per batch
#define P1_GRID 2048               // blocks; each handles NCHUNKS/P1_GRID chunks
#define P1_ITERS (NCHUNKS / P1_GRID)       // 4

#define GLOBAL_AS __attribute__((address_space(1)))
#define LDS_AS    __attribute__((address_space(3)))

// ---------------- Threefry-2x32-20, exactly as jax/_src/prng.py ----------------
struct U2 { uint32_t a, b; };

__host__ __device__ constexpr U2 tf2x32(uint32_t k0, uint32_t k1, uint32_t x0, uint32_t x1) {
  uint32_t ks0 = k0, ks1 = k1, ks2 = k0 ^ k1 ^ 0x1BD11BDAu;
  x0 += ks0; x1 += ks1;
  const int rotA[4] = {13, 15, 26, 6};
  const int rotB[4] = {17, 29, 16, 24};
  for (int r = 0; r < 4; ++r) { x0 += x1; x1 = (x1 << rotA[r]) | (x1 >> (32 - rotA[r])); x1 ^= x0; }
  x0 += ks1; x1 += ks2 + 1u;
  for (int r = 0; r < 4; ++r) { x0 += x1; x1 = (x1 << rotB[r]) | (x1 >> (32 - rotB[r])); x1 ^= x0; }
  x0 += ks2; x1 += ks0 + 2u;
  for (int r = 0; r < 4; ++r) { x0 += x1; x1 = (x1 << rotA[r]) | (x1 >> (32 - rotA[r])); x1 ^= x0; }
  x0 += ks0; x1 += ks1 + 3u;
  for (int r = 0; r < 4; ++r) { x0 += x1; x1 = (x1 << rotB[r]) | (x1 >> (32 - rotB[r])); x1 ^= x0; }
  x0 += ks1; x1 += ks2 + 4u;
  for (int r = 0; r < 4; ++r) { x0 += x1; x1 = (x1 << rotA[r]) | (x1 >> (32 - rotA[r])); x1 ^= x0; }
  x0 += ks2; x1 += ks0 + 5u;
  return U2{x0, x1};
}

// ---------------- Pass 1: dense-frontier DMA-staged mask + per-chunk xyz sums ----------------
// Round-3 post-mortem: three different load structures (scalar, wide-reg, DMA)
// ALL plateau at 2.56 TB/s delivered. Concurrency is not the limiter (6
// blocks/CU x 24 KB in flight >> 9.2 KB latency-BW product). The invariant was
// the mapping: each block owned a private CONTIGUOUS 64 KB span, so the
// instantaneous read frontier was ~2048 scattered streams, phase-aligned mod
// 64 KB across the HBM channel interleave. The two fast kernels on this setup
// (harness fill @6.8 TB/s, m13 copy @6.3 TB/s) both use a dense grid-stride
// frontier. This version keeps the DMA staging identical and only remaps:
// block g processes chunks {g, g+2048, ...} — concurrent chunks are
// CONSECUTIVE in memory, spreading uniformly over all channels.
// (Round 4 failed on infra — resubmitted unchanged for the A/B datum.)
__global__ __launch_bounds__(256) void pass1_kernel(
    const float4* __restrict__ pc, const float* __restrict__ lg,
    float* __restrict__ sumsPartial, unsigned long long* __restrict__ maskWords) {
  __shared__ float4 sPC[STAGE];            // 16 KiB
  __shared__ float  sL0[STAGE];            // 4 KiB
  __shared__ float  sL1[STAGE];            // 4 KiB
  __shared__ float ssx[4], ssy[4], ssz[4];

  const int g = blockIdx.x;
  const int t = threadIdx.x;
  const int lane = t & 63, wv = t >> 6;

  for (int i = 0; i < P1_ITERS; ++i) {
    const int c = i * P1_GRID + g;         // dense frontier: concurrent c are consecutive
    const int b = c >> 7;                  // CHUNKS_PB = 128
    const int o = (c & (CHUNKS_PB - 1)) * STAGE;   // in-batch point offset
    const float4* pcg = pc + (size_t)b * NPTS + o;
    const float*  l0g = lg + (size_t)b * (2 * NPTS) + o;
    const float*  l1g = l0g + NPTS;

    // ---- issue stage DMA (async; no VGPR payload) ----
#pragma unroll
    for (int q = 0; q < 4; ++q) {
      const int pt = wv * 256 + q * 64;    // lane offset added by HW on LDS side
      __builtin_amdgcn_global_load_lds(
          (const GLOBAL_AS void*)(pcg + (pt + lane)),
          (LDS_AS void*)((char*)sPC + (size_t)pt * 16), 16, 0, 0);
    }
    __builtin_amdgcn_global_load_lds(
        (const GLOBAL_AS void*)(l0g + wv * 256 + lane * 4),
        (LDS_AS void*)((char*)sL0 + (size_t)(wv * 256) * 4), 16, 0, 0);
    __builtin_amdgcn_global_load_lds(
        (const GLOBAL_AS void*)(l1g + wv * 256 + lane * 4),
        (LDS_AS void*)((char*)sL1 + (size_t)(wv * 256) * 4), 16, 0, 0);

    __syncthreads();                       // vmcnt(0) drain: DMA landed

    // ---- compute from LDS: thread t handles stage points {t, 256+t, 512+t, 768+t} ----
    float sx = 0.f, sy = 0.f, sz = 0.f;
#pragma unroll
    for (int q = 0; q < 4; ++q) {
      const int ip = q * 256 + t;
      const float a0 = sL0[ip];
      const float a1 = sL1[ip];
      const float4 p = sPC[ip];
      const bool m = a0 < a1;
      const unsigned long long bal = __ballot(m);
      if (lane == 0)
        maskWords[(size_t)b * WORDS_PB + (o >> 6) + q * 4 + wv] = bal;
      if (m) { sx += p.x; sy += p.y; sz += p.z; }
    }

    // per-chunk block reduce (shuffles are in-wave; no sync needed before)
    for (int os = 32; os; os >>= 1) {
      sx += __shfl_down(sx, os, 64);
      sy += __shfl_down(sy, os, 64);
      sz += __shfl_down(sz, os, 64);
    }
    if (lane == 0) { ssx[wv] = sx; ssy[wv] = sy; ssz[wv] = sz; }
    __syncthreads();                       // LDS reads done (stage reuse) + ssx visible
    if (t == 0) {
      sumsPartial[c * 3 + 0] = ssx[0] + ssx[1] + ssx[2] + ssx[3];
      sumsPartial[c * 3 + 1] = ssy[0] + ssy[1] + ssy[2] + ssy[3];
      sumsPartial[c * 3 + 2] = ssz[0] + ssz[1] + ssz[2] + ssz[3];
    }
    // t0's ssx read is ordered before next iter's ssx write by the next
    // iteration's post-DMA __syncthreads.
  }
}

// ---------------- Pass 2 (fused scan + select + gather) ----------------
// 512 blocks, 8 per batch. Reduces the 128 per-chunk partials of its batch.
__global__ __launch_bounds__(256) void pass3_kernel(
    const float4* __restrict__ pc, const float* __restrict__ sumsPartial,
    const unsigned long long* __restrict__ maskWords,
    float* __restrict__ out) {
  const int blk = blockIdx.x;
  const int b = blk >> 3;                  // 8 blocks per batch
  const int t = threadIdx.x;
  const int lane = t & 63, wv = t >> 6;
  const int j = (blk & 7) * 256 + t;
  const int gid = b * MPTS + j;

  __shared__ unsigned long long sW[WORDS_PB];   // 16 KiB
  __shared__ uint32_t sOff[WORDS_PB];           // 8 KiB
  __shared__ int wsum[4];
  __shared__ float pSum[2][3];
  __shared__ float sMean[3];
  __shared__ int sCnt;

  const unsigned long long* mw = maskWords + (size_t)b * WORDS_PB;
#pragma unroll
  for (int k = 0; k < 8; ++k) sW[t + k * 256] = mw[t + k * 256];
  __syncthreads();

  // popcount + exclusive scan of the 2048 words (each thread owns 8 consecutive)
  const int basew = t * 8;
  int p[8];
  int local = 0;
#pragma unroll
  for (int k = 0; k < 8; ++k) { p[k] = __popcll(sW[basew + k]); local += p[k]; }

  int x = local;
#pragma unroll
  for (int o = 1; o < 64; o <<= 1) {
    const int y = __shfl_up(x, o, 64);
    if (lane >= o) x += y;
  }
  if (lane == 63) wsum[wv] = x;

  // waves 0-1: reduce the 128 per-chunk partial sums -> pSum
  if (wv < 2) {
    const float* sp = sumsPartial + ((size_t)b * CHUNKS_PB + t) * 3;
    float px = sp[0], py = sp[1], pz = sp[2];
    for (int o = 32; o; o >>= 1) {
      px += __shfl_down(px, o, 64);
      py += __shfl_down(py, o, 64);
      pz += __shfl_down(pz, o, 64);
    }
    if (lane == 0) { pSum[wv][0] = px; pSum[wv][1] = py; pSum[wv][2] = pz; }
  }
  __syncthreads();

  int add = 0;
#pragma unroll
  for (int u = 0; u < 4; ++u) add += (u < wv) ? wsum[u] : 0;
  int run = add + x - local;
#pragma unroll
  for (int k = 0; k < 8; ++k) { sOff[basew + k] = (uint32_t)run; run += p[k]; }

  if (t == 0) {
    const int ct = wsum[0] + wsum[1] + wsum[2] + wsum[3];
    sCnt = ct;
    const float d = fmaxf((float)ct, 1.0f);
    sMean[0] = (pSum[0][0] + pSum[1][0]) / d;
    sMean[1] = (pSum[0][1] + pSum[1][1]) / d;
    sMean[2] = (pSum[0][2] + pSum[1][2]) / d;
    if ((blk & 7) == 0) {
      float* om = out + (size_t)BATCH * MPTS * 3 + (size_t)b * 3;
      om[0] = sMean[0]; om[1] = sMean[1]; om[2] = sMean[2];
    }
  }
  __syncthreads();

  const int cb = sCnt;
  float ox, oy, oz;
  if (cb == 0) {
    ox = oy = oz = (float)b;               // reference fills empty batches with batch id
  } else {
    constexpr U2 K1 = tf2x32(0u, 42u, 0u, 0u);  // split(key)[0]
    constexpr U2 K2 = tf2x32(0u, 42u, 0u, 1u);  // split(key)[1]
    const uint32_t span = (uint32_t)cb;
    U2 h = tf2x32(K1.a, K1.b, 0u, (uint32_t)gid);
    U2 l = tf2x32(K2.a, K2.b, 0u, (uint32_t)gid);
    uint32_t hb = h.a ^ h.b;               // higher_bits (32-bit fold)
    uint32_t lb = l.a ^ l.b;               // lower_bits
    uint32_t mul = 65536u % span;
    mul = (mul * mul) % span;              // uint32 wrap, exactly as lax
    uint32_t off = ((hb % span) * mul + (lb % span)) % span;
    int r = (j < cb && cb <= MPTS) ? j : (int)off;

    // binary search: largest w with sOff[w] <= r (sOff[0]==0)
    int lo = 0;
#pragma unroll
    for (int step = 1024; step; step >>= 1) {
      const int nxt = lo + step;
      if (nxt < WORDS_PB && sOff[nxt] <= (uint32_t)r) lo = nxt;
    }
    int rem = r - (int)sOff[lo];
    const unsigned long long w = sW[lo];

    // branchless 64-bit rank-select of the rem-th set bit
    uint32_t cur = (uint32_t)w;
    int bitbase = 0;
    int c = __popc(cur);
    if (rem >= c) { rem -= c; cur = (uint32_t)(w >> 32); bitbase = 32; }
    c = __popc(cur & 0xFFFFu); if (rem >= c) { rem -= c; cur >>= 16; bitbase += 16; }
    c = __popc(cur & 0xFFu);   if (rem >= c) { rem -= c; cur >>= 8;  bitbase += 8;  }
    c = __popc(cur & 0xFu);    if (rem >= c) { rem -= c; cur >>= 4;  bitbase += 4;  }
    c = __popc(cur & 0x3u);    if (rem >= c) { rem -= c; cur >>= 2;  bitbase += 2;  }
    c = (int)(cur & 1u);       if (rem >= c) {           cur >>= 1;  bitbase += 1;  }
    const int idx = lo * 64 + bitbase;

    const float4 pnt = pc[(size_t)b * NPTS + idx];
    ox = pnt.x - sMean[0]; oy = pnt.y - sMean[1]; oz = pnt.z - sMean[2];
  }
  float* o = out + (size_t)gid * 3;
  o[0] = ox; o[1] = oy; o[2] = oz;
}

// ---------------- launch ----------------
extern "C" void kernel_launch(void* const* d_in, const int* in_sizes, int n_in,
                              void* d_out, int out_size, void* d_ws, size_t ws_size,
                              hipStream_t stream) {
  const float4* pc = (const float4*)d_in[0];   // (B, N, 4) float32
  const float*  lg = (const float*)d_in[1];    // (B, 2, N) float32
  float* out = (float*)d_out;                  // obj (B,M,3) then mean (B,3)

  char* w = (char*)d_ws;
  float* sumsPartial = (float*)(w + 0);                    // 8192*3 floats = 98304 B
  unsigned long long* maskWords =
      (unsigned long long*)(w + 98304);                    // 64*2048 u64 = 1 MiB

  pass1_kernel<<<P1_GRID, 256, 0, stream>>>(pc, lg, sumsPartial, maskWords);
  pass3_kernel<<<(BATCH * MPTS) / 256, 256, 0, stream>>>(pc, sumsPartial, maskWords, out);
}